// Round 2
// baseline (828.313 us; speedup 1.0000x reference)
//
#include <hip/hip_runtime.h>
#include <stdint.h>

#define N_NODES 100000
#define N_EDGES 3200000
#define D_FEAT 256
#define NROWBLK 391   // ceil(N_NODES / 256)
#define EPB 2048      // edges per gemm block for fused histogram (1563*2048 >= N_EDGES)

typedef __attribute__((ext_vector_type(8))) short short8;
typedef __attribute__((ext_vector_type(8))) ushort ushort8;
typedef __attribute__((ext_vector_type(4))) float float4v;

__device__ inline unsigned short f2bf(float f) {
    union { float f; unsigned u; } v; v.f = f;
    unsigned u = v.u;
    u += 0x7FFF + ((u >> 16) & 1);   // round-to-nearest-even
    return (unsigned short)(u >> 16);
}
__device__ inline float bf2f(unsigned short u) {
    union { unsigned u; float f; } v; v.u = (unsigned)u << 16;
    return v.f;
}

// ---- prep: W fp32 -> bf16, and zero the row histogram --------------------
__global__ __launch_bounds__(256) void prep_kernel(const float* __restrict__ W,
                                                   ushort* __restrict__ Wbf,
                                                   int* __restrict__ row_cnt) {
    int b = blockIdx.x;
    if (b < 256) {
        int i = b * 256 + threadIdx.x;           // 65536 W elements, exact
        Wbf[i] = f2bf(W[i]);
    } else {
        int i = (b - 256) * 256 + threadIdx.x;   // 391 blocks cover 100096
        if (i < N_NODES) row_cnt[i] = 0;
    }
}

// ---- GEMM first: y = x @ W^T, with fused per-row edge histogram ----------
// 64 rows/block, 4 waves each own 64 output cols; MFMA 16x16x32 bf16.
// The histogram atomics are fire-and-forget and overlap the memory-bound GEMM.
__global__ __launch_bounds__(256) void gemm_x_kernel(
        const float* __restrict__ x,      // [N][256] fp32
        const ushort* __restrict__ Wbf,   // [256][256] bf16, n-major
        const int* __restrict__ erow,
        int* __restrict__ row_cnt,
        ushort* __restrict__ ybf) {       // [N][256] bf16
    // fused histogram: this block's slice of edges
    int eb = blockIdx.x * EPB;
    #pragma unroll
    for (int j = 0; j < EPB; j += 256) {
        int i = eb + j + threadIdx.x;
        if (i < N_EDGES) atomicAdd(&row_cnt[erow[i]], 1);
    }

    int w    = threadIdx.x >> 6;
    int lane = threadIdx.x & 63;
    int quad = lane >> 4;
    int l16  = lane & 15;
    int rt   = blockIdx.x * 64;           // 1563 blocks

    float4v acc[4][4];
    #pragma unroll
    for (int mt = 0; mt < 4; ++mt)
        #pragma unroll
        for (int nt = 0; nt < 4; ++nt) acc[mt][nt] = (float4v){0.f, 0.f, 0.f, 0.f};

    #pragma unroll
    for (int k0 = 0; k0 < 256; k0 += 32) {
        short8 a[4], bf[4];
        #pragma unroll
        for (int mt = 0; mt < 4; ++mt) {
            int row = rt + mt * 16 + l16;
            if (row >= N_NODES) row = N_NODES - 1;   // clamp (tail block)
            const float4v* p = (const float4v*)&x[(size_t)row * 256 + k0 + quad * 8];
            float4v f0 = p[0], f1 = p[1];
            a[mt][0] = (short)f2bf(f0.x); a[mt][1] = (short)f2bf(f0.y);
            a[mt][2] = (short)f2bf(f0.z); a[mt][3] = (short)f2bf(f0.w);
            a[mt][4] = (short)f2bf(f1.x); a[mt][5] = (short)f2bf(f1.y);
            a[mt][6] = (short)f2bf(f1.z); a[mt][7] = (short)f2bf(f1.w);
        }
        #pragma unroll
        for (int nt = 0; nt < 4; ++nt) {
            int n = w * 64 + nt * 16 + l16;
            bf[nt] = *(const short8*)&Wbf[n * 256 + k0 + quad * 8];
        }
        #pragma unroll
        for (int mt = 0; mt < 4; ++mt)
            #pragma unroll
            for (int nt = 0; nt < 4; ++nt)
                acc[mt][nt] = __builtin_amdgcn_mfma_f32_16x16x32_bf16(a[mt], bf[nt], acc[mt][nt], 0, 0, 0);
    }
    #pragma unroll
    for (int mt = 0; mt < 4; ++mt)
        #pragma unroll
        for (int nt = 0; nt < 4; ++nt) {
            int n = w * 64 + nt * 16 + l16;
            #pragma unroll
            for (int r = 0; r < 4; ++r) {
                int row = rt + mt * 16 + quad * 4 + r;   // C/D: col=lane&15, row=quad*4+reg
                if (row < N_NODES) ybf[(size_t)row * 256 + n] = f2bf(acc[mt][nt][r]);
            }
        }
}

// ---- scan A: per-256-row block exclusive scan of row_cnt; emit totals ----
__global__ __launch_bounds__(256) void scan_rows(const int* __restrict__ row_cnt,
                                                 int* __restrict__ row_start,
                                                 int* __restrict__ totals) {
    __shared__ int s[256];
    int b = blockIdx.x, t = threadIdx.x;
    int row = b * 256 + t;
    int c = (row < N_NODES) ? row_cnt[row] : 0;
    s[t] = c;
    __syncthreads();
    for (int o = 1; o < 256; o <<= 1) {
        int x = (t >= o) ? s[t - o] : 0;
        __syncthreads();
        s[t] += x;
        __syncthreads();
    }
    if (row < N_NODES) row_start[row] = s[t] - c;   // local exclusive, base added later
    if (t == 255) totals[b] = s[t];
}

// ---- scan B: exclusive scan of 391 block totals -> bases -----------------
__global__ __launch_bounds__(512) void scan_buckets(const int* __restrict__ totals,
                                                    int* __restrict__ base_,
                                                    int* __restrict__ row_start) {
    __shared__ int s[512];
    int t = threadIdx.x;
    int v = (t < NROWBLK) ? totals[t] : 0;
    s[t] = v;
    __syncthreads();
    for (int o = 1; o < 512; o <<= 1) {
        int x = (t >= o) ? s[t - o] : 0;
        __syncthreads();
        s[t] += x;
        __syncthreads();
    }
    if (t < NROWBLK) base_[t] = s[t] - v;
    if (t == 0) row_start[N_NODES] = N_EDGES;
}

// ---- scan C: finalize row_start and init scatter cursors -----------------
__global__ __launch_bounds__(256) void finalize_rows(int* __restrict__ row_start,
                                                     const int* __restrict__ base_,
                                                     int* __restrict__ cursor) {
    int i = blockIdx.x * 256 + threadIdx.x;
    if (i < N_NODES) {
        int v = row_start[i] + base_[i >> 8];
        row_start[i] = v;
        cursor[i] = v;
    }
}

// ---- scatter: direct atomic CSR build (order within row irrelevant) ------
// 8B writes land within 256B per-row ranges; L2 write-back coalesces them.
__global__ __launch_bounds__(256) void scatter_kernel(
        const int* __restrict__ erow, const int* __restrict__ ecol,
        const float* __restrict__ eval,
        int* __restrict__ cursor, uint2* __restrict__ csr) {
    int i = blockIdx.x * 256 + threadIdx.x;   // 12500 blocks, exact
    int r = erow[i];
    int dst = atomicAdd(&cursor[r], 1);
    uint2 cv;
    cv.x = (unsigned)ecol[i];
    union { float f; unsigned u; } w; w.f = eval[i];
    cv.y = w.u;
    csr[dst] = cv;
}

// ---- SpMM over projected y: one wave per row, half-wave per edge ---------
// Writes final fp32 output directly.
__global__ __launch_bounds__(256) void spmm_kernel(
        const ushort* __restrict__ ybf,           // [N][256] bf16
        const int* __restrict__ row_start,
        const uint2* __restrict__ csr_cv,         // {col, val_bits}
        float* __restrict__ out) {                // [N][256] fp32
    int row  = (blockIdx.x * blockDim.x + threadIdx.x) >> 6;
    int lane = threadIdx.x & 63;
    int half = lane >> 5;
    int hl   = lane & 31;
    if (row >= N_NODES) return;
    int start = row_start[row];
    int end   = row_start[row + 1];
    float acc[8] = {0.f, 0.f, 0.f, 0.f, 0.f, 0.f, 0.f, 0.f};
    int e = start + half;
    for (; e + 6 < end; e += 8) {                 // 4 edges per half-wave iter
        uint2 cv0 = csr_cv[e];
        uint2 cv1 = csr_cv[e + 2];
        uint2 cv2 = csr_cv[e + 4];
        uint2 cv3 = csr_cv[e + 6];
        ushort8 v0 = *(const ushort8*)&ybf[(size_t)cv0.x * 256 + hl * 8];
        ushort8 v1 = *(const ushort8*)&ybf[(size_t)cv1.x * 256 + hl * 8];
        ushort8 v2 = *(const ushort8*)&ybf[(size_t)cv2.x * 256 + hl * 8];
        ushort8 v3 = *(const ushort8*)&ybf[(size_t)cv3.x * 256 + hl * 8];
        union { unsigned u; float f; } w0, w1, w2, w3;
        w0.u = cv0.y; w1.u = cv1.y; w2.u = cv2.y; w3.u = cv3.y;
        #pragma unroll
        for (int j = 0; j < 8; ++j) acc[j] += w0.f * bf2f(v0[j]);
        #pragma unroll
        for (int j = 0; j < 8; ++j) acc[j] += w1.f * bf2f(v1[j]);
        #pragma unroll
        for (int j = 0; j < 8; ++j) acc[j] += w2.f * bf2f(v2[j]);
        #pragma unroll
        for (int j = 0; j < 8; ++j) acc[j] += w3.f * bf2f(v3[j]);
    }
    for (; e < end; e += 2) {
        uint2 cv = csr_cv[e];
        ushort8 v = *(const ushort8*)&ybf[(size_t)cv.x * 256 + hl * 8];
        union { unsigned u; float f; } w; w.u = cv.y;
        #pragma unroll
        for (int j = 0; j < 8; ++j) acc[j] += w.f * bf2f(v[j]);
    }
    #pragma unroll
    for (int j = 0; j < 8; ++j) acc[j] += __shfl_xor(acc[j], 32, 64);
    if (half == 0) {
        float4v o0 = {acc[0], acc[1], acc[2], acc[3]};
        float4v o1 = {acc[4], acc[5], acc[6], acc[7]};
        *(float4v*)&out[(size_t)row * 256 + hl * 8]     = o0;
        *(float4v*)&out[(size_t)row * 256 + hl * 8 + 4] = o1;
    }
}

// ---- launch --------------------------------------------------------------

extern "C" void kernel_launch(void* const* d_in, const int* in_sizes, int n_in,
                              void* d_out, int out_size, void* d_ws, size_t ws_size,
                              hipStream_t stream) {
    const float* x    = (const float*)d_in[0];
    const int*   erow = (const int*)d_in[1];
    const int*   ecol = (const int*)d_in[2];
    const float* eval = (const float*)d_in[3];
    const float* W    = (const float*)d_in[4];
    float* out = (float*)d_out;

    char* ws = (char*)d_ws;
    size_t off = 0;
    int* row_cnt   = (int*)(ws + off);   off += ((size_t)N_NODES * 4 + 255) & ~255ull;
    int* row_start = (int*)(ws + off);   off += ((size_t)(N_NODES + 1) * 4 + 255) & ~255ull;
    int* cursor    = (int*)(ws + off);   off += ((size_t)N_NODES * 4 + 255) & ~255ull;
    int* totals    = (int*)(ws + off);   off += ((size_t)NROWBLK * 4 + 255) & ~255ull;
    int* base_     = (int*)(ws + off);   off += ((size_t)NROWBLK * 4 + 255) & ~255ull;
    uint2* csr_cv  = (uint2*)(ws + off); off += (size_t)N_EDGES * 8;
    ushort* Wbf    = (ushort*)(ws + off);  off += (size_t)D_FEAT * D_FEAT * 2;
    ushort* ybf    = (ushort*)(ws + off);  off += (size_t)N_NODES * D_FEAT * 2;

    // prep: W->bf16 + zero histogram
    prep_kernel<<<256 + NROWBLK, 256, 0, stream>>>(W, Wbf, row_cnt);
    // projection first (agg and projection commute): y = x @ W^T, + fused row hist
    gemm_x_kernel<<<(N_NODES + 63) / 64, 256, 0, stream>>>(x, Wbf, erow, row_cnt, ybf);
    // CSR offsets: block scan -> bucket scan -> finalize/cursor init
    scan_rows<<<NROWBLK, 256, 0, stream>>>(row_cnt, row_start, totals);
    scan_buckets<<<1, 512, 0, stream>>>(totals, base_, row_start);
    finalize_rows<<<NROWBLK, 256, 0, stream>>>(row_start, base_, cursor);
    // direct atomic scatter into CSR
    scatter_kernel<<<N_EDGES / 256, 256, 0, stream>>>(erow, ecol, eval, cursor, csr_cv);
    // aggregate projected features straight into the fp32 output
    spmm_kernel<<<N_NODES / 4, 256, 0, stream>>>(ybf, row_start, csr_cv, out);
}

// Round 3
// 615.448 us; speedup vs baseline: 1.3459x; 1.3459x over previous
//
#include <hip/hip_runtime.h>
#include <stdint.h>

#define N_NODES 100000
#define N_EDGES 3200000
#define D_FEAT 256
#define CHUNK 8192
#define NBLK_E 391            // ceil(N_EDGES / CHUNK)
#define NB1 25                // super-buckets: row >> 12 (4096 rows each)
#define NB2 391               // fine buckets:  row >> 8  (256 rows each)

typedef __attribute__((ext_vector_type(8))) short short8;
typedef __attribute__((ext_vector_type(8))) ushort ushort8;
typedef __attribute__((ext_vector_type(4))) float float4v;

__device__ inline unsigned short f2bf(float f) {
    union { float f; unsigned u; } v; v.f = f;
    unsigned u = v.u;
    u += 0x7FFF + ((u >> 16) & 1);   // round-to-nearest-even
    return (unsigned short)(u >> 16);
}
__device__ inline float bf2f(unsigned short u) {
    union { unsigned u; float f; } v; v.u = (unsigned)u << 16;
    return v.f;
}

// ---- W fp32 -> bf16 ------------------------------------------------------
__global__ void wconv_kernel(const float* __restrict__ W, ushort* __restrict__ Wbf) {
    int i = blockIdx.x * 256 + threadIdx.x;
    Wbf[i] = f2bf(W[i]);
}

// ---- GEMM first: y = x @ W^T (projection and aggregation commute) --------
__global__ __launch_bounds__(256) void gemm_x_kernel(
        const float* __restrict__ x,      // [N][256] fp32
        const ushort* __restrict__ Wbf,   // [256][256] bf16, n-major
        ushort* __restrict__ ybf) {       // [N][256] bf16
    int w    = threadIdx.x >> 6;
    int lane = threadIdx.x & 63;
    int quad = lane >> 4;
    int l16  = lane & 15;
    int rt   = blockIdx.x * 64;           // 1563 blocks

    float4v acc[4][4];
    #pragma unroll
    for (int mt = 0; mt < 4; ++mt)
        #pragma unroll
        for (int nt = 0; nt < 4; ++nt) acc[mt][nt] = (float4v){0.f, 0.f, 0.f, 0.f};

    #pragma unroll
    for (int k0 = 0; k0 < 256; k0 += 32) {
        short8 a[4], bf[4];
        #pragma unroll
        for (int mt = 0; mt < 4; ++mt) {
            int row = rt + mt * 16 + l16;
            if (row >= N_NODES) row = N_NODES - 1;   // clamp (tail block)
            const float4v* p = (const float4v*)&x[(size_t)row * 256 + k0 + quad * 8];
            float4v f0 = p[0], f1 = p[1];
            a[mt][0] = (short)f2bf(f0.x); a[mt][1] = (short)f2bf(f0.y);
            a[mt][2] = (short)f2bf(f0.z); a[mt][3] = (short)f2bf(f0.w);
            a[mt][4] = (short)f2bf(f1.x); a[mt][5] = (short)f2bf(f1.y);
            a[mt][6] = (short)f2bf(f1.z); a[mt][7] = (short)f2bf(f1.w);
        }
        #pragma unroll
        for (int nt = 0; nt < 4; ++nt) {
            int n = w * 64 + nt * 16 + l16;
            bf[nt] = *(const short8*)&Wbf[n * 256 + k0 + quad * 8];
        }
        #pragma unroll
        for (int mt = 0; mt < 4; ++mt)
            #pragma unroll
            for (int nt = 0; nt < 4; ++nt)
                acc[mt][nt] = __builtin_amdgcn_mfma_f32_16x16x32_bf16(a[mt], bf[nt], acc[mt][nt], 0, 0, 0);
    }
    #pragma unroll
    for (int mt = 0; mt < 4; ++mt)
        #pragma unroll
        for (int nt = 0; nt < 4; ++nt) {
            int n = w * 64 + nt * 16 + l16;
            #pragma unroll
            for (int r = 0; r < 4; ++r) {
                int row = rt + mt * 16 + quad * 4 + r;   // C/D: col=lane&15, row=quad*4+reg
                if (row < N_NODES) ybf[(size_t)row * 256 + n] = f2bf(acc[mt][nt][r]);
            }
        }
}

// ---- L1 hist: 25 super-buckets per chunk ---------------------------------
__global__ __launch_bounds__(256) void hist1_kernel(const int* __restrict__ erow,
                                                    int* __restrict__ hist) {
    __shared__ int cnt[NB1];
    if (threadIdx.x < NB1) cnt[threadIdx.x] = 0;
    __syncthreads();
    int cb = blockIdx.x * CHUNK;
    for (int j = 0; j < CHUNK; j += 256) {
        int i = cb + j + threadIdx.x;
        if (i < N_EDGES) atomicAdd(&cnt[erow[i] >> 12], 1);
    }
    __syncthreads();
    if (threadIdx.x < NB1) hist[blockIdx.x * NB1 + threadIdx.x] = cnt[threadIdx.x];
}

// ---- L2 hist: 391 fine buckets per chunk (over grouped rh1 stream) -------
__global__ __launch_bounds__(256) void hist2_kernel(const ushort* __restrict__ rh1,
                                                    int* __restrict__ hist) {
    __shared__ int cnt[NB2];
    for (int b = threadIdx.x; b < NB2; b += 256) cnt[b] = 0;
    __syncthreads();
    int cb = blockIdx.x * CHUNK;
    for (int j = 0; j < CHUNK; j += 256) {
        int i = cb + j + threadIdx.x;
        if (i < N_EDGES) atomicAdd(&cnt[rh1[i]], 1);
    }
    __syncthreads();
    for (int b = threadIdx.x; b < NB2; b += 256)
        hist[blockIdx.x * NB2 + b] = cnt[b];
}

// ---- per-bucket exclusive scan over chunk entries; emit totals -----------
__global__ __launch_bounds__(512) void scan_blocks(int* __restrict__ hist,
                                                   int* __restrict__ totals,
                                                   int nbkt) {
    __shared__ int s[512];
    int b = blockIdx.x;          // bucket
    int t = threadIdx.x;
    int v = (t < NBLK_E) ? hist[t * nbkt + b] : 0;
    s[t] = v;
    __syncthreads();
    for (int o = 1; o < 512; o <<= 1) {
        int x = (t >= o) ? s[t - o] : 0;
        __syncthreads();
        s[t] += x;
        __syncthreads();
    }
    if (t < NBLK_E) hist[t * nbkt + b] = s[t] - v;   // exclusive within bucket
    if (t == NBLK_E - 1) totals[b] = s[t];
}

// ---- exclusive scan of bucket totals -> bucket bases ---------------------
__global__ __launch_bounds__(512) void scan_buckets(const int* __restrict__ totals,
                                                    int* __restrict__ base_,
                                                    int n, int* __restrict__ row_start) {
    __shared__ int s[512];
    int t = threadIdx.x;
    int v = (t < n) ? totals[t] : 0;
    s[t] = v;
    __syncthreads();
    for (int o = 1; o < 512; o <<= 1) {
        int x = (t >= o) ? s[t - o] : 0;
        __syncthreads();
        s[t] += x;
        __syncthreads();
    }
    if (t < n) base_[t] = s[t] - v;
    if (t == 0) {
        base_[n] = N_EDGES;
        if (row_start) row_start[N_NODES] = N_EDGES;
    }
}

// ---- L1 scatter: group edges by super-bucket (long coalesced runs) -------
// Emits rh1 (row>>8, ushort) + packed payload {col | (row&255)<<17, val}.
__global__ __launch_bounds__(256) void scatter1_kernel(
        const int* __restrict__ erow, const int* __restrict__ ecol,
        const float* __restrict__ eval,
        const int* __restrict__ hist1, const int* __restrict__ base1,
        ushort* __restrict__ rh1, uint2* __restrict__ cv1) {
    __shared__ int lbase[NB1];
    __shared__ int cnt[NB1];
    int t = threadIdx.x;
    if (t < NB1) {
        lbase[t] = hist1[blockIdx.x * NB1 + t] + base1[t];
        cnt[t] = 0;
    }
    __syncthreads();
    int cb = blockIdx.x * CHUNK;
    for (int j = 0; j < CHUNK; j += 256) {
        int i = cb + j + t;
        if (i < N_EDGES) {
            int r = erow[i];
            int b = r >> 12;
            int pos = lbase[b] + atomicAdd(&cnt[b], 1);
            rh1[pos] = (unsigned short)(r >> 8);
            uint2 cv;
            cv.x = (unsigned)ecol[i] | ((unsigned)(r & 255) << 17);  // col < 2^17
            union { float f; unsigned u; } w; w.f = eval[i];
            cv.y = w.u;
            cv1[pos] = cv;
        }
    }
}

// ---- L2 scatter: grouped stream -> 391 fine buckets (long runs) ----------
__global__ __launch_bounds__(256) void scatter2_kernel(
        const ushort* __restrict__ rh1, const uint2* __restrict__ cv1,
        const int* __restrict__ hist2, const int* __restrict__ base2,
        uint2* __restrict__ tmp2) {
    __shared__ int lbase[NB2];
    __shared__ int cnt[NB2];
    for (int b = threadIdx.x; b < NB2; b += 256) {
        lbase[b] = hist2[blockIdx.x * NB2 + b] + base2[b];
        cnt[b] = 0;
    }
    __syncthreads();
    int cb = blockIdx.x * CHUNK;
    for (int j = 0; j < CHUNK; j += 256) {
        int i = cb + j + threadIdx.x;
        if (i < N_EDGES) {
            int b = rh1[i];
            int pos = lbase[b] + atomicAdd(&cnt[b], 1);
            tmp2[pos] = cv1[i];
        }
    }
}

// ---- fine counting sort within each 256-row bucket; final CSR ------------
// Scatter window is 64 KB (L2-resident) -> full-line writebacks.
__global__ __launch_bounds__(256) void fine_sort(const uint2* __restrict__ tmp,
                                                 const int* __restrict__ base_,
                                                 uint2* __restrict__ csr,
                                                 int* __restrict__ row_start) {
    __shared__ int cnt[256];
    __shared__ int excl[256];
    int b = blockIdx.x;
    int t = threadIdx.x;
    int s0 = base_[b];
    int nb = base_[b + 1] - s0;
    cnt[t] = 0;
    __syncthreads();
    for (int j = t; j < nb; j += 256)
        atomicAdd(&cnt[tmp[s0 + j].x >> 17], 1);
    __syncthreads();
    int v = cnt[t];
    excl[t] = v;
    __syncthreads();
    for (int o = 1; o < 256; o <<= 1) {
        int x = (t >= o) ? excl[t - o] : 0;
        __syncthreads();
        excl[t] += x;
        __syncthreads();
    }
    int ex = excl[t] - v;            // exclusive prefix for row_low == t
    int row = b * 256 + t;
    if (row < N_NODES) row_start[row] = s0 + ex;
    excl[t] = ex;                    // own-slot overwrite, safe
    cnt[t] = 0;                      // reuse as cursor
    __syncthreads();
    for (int j = t; j < nb; j += 256) {
        uint2 cv = tmp[s0 + j];
        unsigned rl = cv.x >> 17;
        int dst = s0 + excl[rl] + atomicAdd(&cnt[rl], 1);
        csr[dst] = cv;
    }
}

// ---- SpMM over projected y: one wave per row, half-wave per edge ---------
__global__ __launch_bounds__(256) void spmm_kernel(
        const ushort* __restrict__ ybf,           // [N][256] bf16
        const int* __restrict__ row_start,
        const uint2* __restrict__ csr_cv,         // col in low 17 bits of .x
        float* __restrict__ out) {                // [N][256] fp32
    int row  = (blockIdx.x * blockDim.x + threadIdx.x) >> 6;
    int lane = threadIdx.x & 63;
    int half = lane >> 5;
    int hl   = lane & 31;
    if (row >= N_NODES) return;
    int start = row_start[row];
    int end   = row_start[row + 1];
    float acc[8] = {0.f, 0.f, 0.f, 0.f, 0.f, 0.f, 0.f, 0.f};
    int e = start + half;
    for (; e + 6 < end; e += 8) {                 // 4 edges per half-wave iter
        uint2 cv0 = csr_cv[e];
        uint2 cv1 = csr_cv[e + 2];
        uint2 cv2 = csr_cv[e + 4];
        uint2 cv3 = csr_cv[e + 6];
        ushort8 v0 = *(const ushort8*)&ybf[(size_t)(cv0.x & 0x1FFFF) * 256 + hl * 8];
        ushort8 v1 = *(const ushort8*)&ybf[(size_t)(cv1.x & 0x1FFFF) * 256 + hl * 8];
        ushort8 v2 = *(const ushort8*)&ybf[(size_t)(cv2.x & 0x1FFFF) * 256 + hl * 8];
        ushort8 v3 = *(const ushort8*)&ybf[(size_t)(cv3.x & 0x1FFFF) * 256 + hl * 8];
        union { unsigned u; float f; } w0, w1, w2, w3;
        w0.u = cv0.y; w1.u = cv1.y; w2.u = cv2.y; w3.u = cv3.y;
        #pragma unroll
        for (int j = 0; j < 8; ++j) acc[j] += w0.f * bf2f(v0[j]);
        #pragma unroll
        for (int j = 0; j < 8; ++j) acc[j] += w1.f * bf2f(v1[j]);
        #pragma unroll
        for (int j = 0; j < 8; ++j) acc[j] += w2.f * bf2f(v2[j]);
        #pragma unroll
        for (int j = 0; j < 8; ++j) acc[j] += w3.f * bf2f(v3[j]);
    }
    for (; e < end; e += 2) {
        uint2 cv = csr_cv[e];
        ushort8 v = *(const ushort8*)&ybf[(size_t)(cv.x & 0x1FFFF) * 256 + hl * 8];
        union { unsigned u; float f; } w; w.u = cv.y;
        #pragma unroll
        for (int j = 0; j < 8; ++j) acc[j] += w.f * bf2f(v[j]);
    }
    #pragma unroll
    for (int j = 0; j < 8; ++j) acc[j] += __shfl_xor(acc[j], 32, 64);
    if (half == 0) {
        float4v o0 = {acc[0], acc[1], acc[2], acc[3]};
        float4v o1 = {acc[4], acc[5], acc[6], acc[7]};
        *(float4v*)&out[(size_t)row * 256 + hl * 8]     = o0;
        *(float4v*)&out[(size_t)row * 256 + hl * 8 + 4] = o1;
    }
}

// ---- launch --------------------------------------------------------------

extern "C" void kernel_launch(void* const* d_in, const int* in_sizes, int n_in,
                              void* d_out, int out_size, void* d_ws, size_t ws_size,
                              hipStream_t stream) {
    const float* x    = (const float*)d_in[0];
    const int*   erow = (const int*)d_in[1];
    const int*   ecol = (const int*)d_in[2];
    const float* eval = (const float*)d_in[3];
    const float* W    = (const float*)d_in[4];
    float* out = (float*)d_out;

    char* ws = (char*)d_ws;
    size_t off = 0;
    int* hist1     = (int*)(ws + off);   off += ((size_t)NBLK_E * NB1 * 4 + 255) & ~255ull;
    int* hist2     = (int*)(ws + off);   off += ((size_t)NBLK_E * NB2 * 4 + 255) & ~255ull;
    int* totals1   = (int*)(ws + off);   off += (512 * 4);
    int* base1     = (int*)(ws + off);   off += (512 * 4);
    int* totals2   = (int*)(ws + off);   off += (512 * 4);
    int* base2     = (int*)(ws + off);   off += (512 * 4);
    int* row_start = (int*)(ws + off);   off += ((size_t)(N_NODES + 1) * 4 + 255) & ~255ull;
    ushort* rh1    = (ushort*)(ws + off); off += ((size_t)N_EDGES * 2 + 255) & ~255ull;
    uint2* cv1     = (uint2*)(ws + off);  off += (size_t)N_EDGES * 8;
    uint2* tmp2    = (uint2*)(ws + off);  off += (size_t)N_EDGES * 8;
    uint2* csr_cv  = (uint2*)(ws + off);  off += (size_t)N_EDGES * 8;
    ushort* Wbf    = (ushort*)(ws + off); off += (size_t)D_FEAT * D_FEAT * 2;
    ushort* ybf    = (ushort*)(ws + off); off += (size_t)N_NODES * D_FEAT * 2;

    // projection first: y = x @ W^T
    wconv_kernel<<<(D_FEAT * D_FEAT) / 256, 256, 0, stream>>>(W, Wbf);
    gemm_x_kernel<<<(N_NODES + 63) / 64, 256, 0, stream>>>(x, Wbf, ybf);

    // CSR build: 25-bucket grouping -> 391-bucket grouping -> fine sort
    hist1_kernel<<<NBLK_E, 256, 0, stream>>>(erow, hist1);
    scan_blocks<<<NB1, 512, 0, stream>>>(hist1, totals1, NB1);
    scan_buckets<<<1, 512, 0, stream>>>(totals1, base1, NB1, nullptr);
    scatter1_kernel<<<NBLK_E, 256, 0, stream>>>(erow, ecol, eval, hist1, base1, rh1, cv1);
    hist2_kernel<<<NBLK_E, 256, 0, stream>>>(rh1, hist2);
    scan_blocks<<<NB2, 512, 0, stream>>>(hist2, totals2, NB2);
    scan_buckets<<<1, 512, 0, stream>>>(totals2, base2, NB2, row_start);
    scatter2_kernel<<<NBLK_E, 256, 0, stream>>>(rh1, cv1, hist2, base2, tmp2);
    fine_sort<<<NB2, 256, 0, stream>>>(tmp2, base2, csr_cv, row_start);

    // aggregate projected features straight into the fp32 output
    spmm_kernel<<<N_NODES / 4, 256, 0, stream>>>(ybf, row_start, csr_cv, out);
}